// Round 13
// baseline (278.976 us; speedup 1.0000x reference)
//
#include <hip/hip_runtime.h>

// B=4,S=2048,H=16,D=64. scores/8, mask->1e-20(~0), softmax, PV.
// Round 13: "R11 done right". Wave owns 32 q-rows (qt=2), kv-step=64 ->
// mask chunks 256B contiguous per row (2x R8's 128B DRAM granularity).
// gll mapping: gll i = 4 rows x 16 granules, source granule XOR-swizzled by
// (row&7), linear LDS dest (rule: gll dest is base+lane*16). Compute reads
// slot (kt*4+g)^(c&7): minimal bank pattern (R11's bug was 8-way conflicts).
// Same occupancy as R8: 64KB/block, 2 blocks/CU, 8 waves/CU.
// Masked positions -> exp2(0)=1, matching ref's 1e-20 pre-softmax semantics.

typedef __attribute__((ext_vector_type(8))) short short8;
typedef __attribute__((ext_vector_type(4))) float f32x4;
typedef __attribute__((ext_vector_type(4))) int   i32x4;
typedef unsigned int u32;

#define MFMA(a, b, c) __builtin_amdgcn_mfma_f32_16x16x32_bf16((a), (b), (c), 0, 0, 0)

static __device__ __forceinline__ short f2bf(float f) {
    __bf16 h = (__bf16)f;
    return __builtin_bit_cast(short, h);
}

static __device__ __forceinline__ void gll16(const int* src, int* dst) {
    __builtin_amdgcn_global_load_lds(
        (const __attribute__((address_space(1))) void*)src,
        (__attribute__((address_space(3))) void*)dst, 16, 0, 0);
}

constexpr int S_ = 2048, HD_ = 1024, STEPS_ = 32;
constexpr long KP_ELEMS = 64L * 32 * 4 * 2 * 64 * 8;   // 8,388,608 bf16 per tensor

// ---- prepack: thread t packs K-fragment t and V-fragment t (as R8).
__global__ __launch_bounds__(256) void prepack_kv(const float* __restrict__ K,
                                                  const float* __restrict__ V,
                                                  short* __restrict__ Kp,
                                                  short* __restrict__ Vp) {
    int t = blockIdx.x * 256 + threadIdx.x;
    int lane = t & 63, hf = (t >> 6) & 1, kt = (t >> 7) & 3, step = (t >> 9) & 31, bh = t >> 14;
    int g = lane >> 4, c = lane & 15, b = bh >> 4, h = bh & 15;

    {   // K: lane holds K[b, step*64+kt*16+c, h, hf*32+g*8 .. +7]
        int row = step * 64 + kt * 16 + c;
        const float* src = K + (long)(b * S_ + row) * HD_ + h * 64 + hf * 32 + g * 8;
        f32x4 x0 = *(const f32x4*)src, x1 = *(const f32x4*)(src + 4);
        short8 o;
        o[0] = f2bf(x0[0]); o[1] = f2bf(x0[1]); o[2] = f2bf(x0[2]); o[3] = f2bf(x0[3]);
        o[4] = f2bf(x1[0]); o[5] = f2bf(x1[1]); o[6] = f2bf(x1[2]); o[7] = f2bf(x1[3]);
        *(short8*)(Kp + (long)t * 8) = o;
    }
    {   // V (kt plays dt): kappa-ordered V^T fragment
        int col = kt * 16 + c, row0 = step * 64 + hf * 32;
        const float* vb = V + (long)(b * S_) * HD_ + h * 64 + col;
        short8 o;
#pragma unroll
        for (int i = 0; i < 8; ++i) {
            int row = row0 + ((i < 4) ? g * 4 + i : 16 + g * 4 + (i - 4));
            o[i] = f2bf(vb[(long)row * HD_]);
        }
        *(short8*)(Vp + (long)t * 8) = o;
    }
}

// ---- main kernel: 1024 blocks x 256 thr; wave owns 32 q-rows; 32 steps of 64 kv.
// Per-wave LDS: 2 bufs x 2048 ints (8KB each). Buf layout: [row][slot], row
// 0..31 (64 ints each), slot 0..15 (16B granules). Slot s of row r holds mask
// ints for kv granule (s ^ (r&7)) of this step (XOR pre-applied at the SOURCE
// address; gll dest stays linear base+lane*16).
// gll i (i=0..7): lane l -> row r = i*4 + (l>>4), src granule (l&15)^(r&7).
__global__ __launch_bounds__(256, 2)
void attn_gll(const float* __restrict__ Q, const short* __restrict__ Kp,
              const short* __restrict__ Vp, const int* __restrict__ M,
              float* __restrict__ O)
{
    const float QSCALE = 0.125f * 1.44269504088896340736f;  // 1/sqrt(64) * log2(e)

    __shared__ int smem[16384];   // 64 KiB: 4 waves x 2 bufs x 2048 ints

    // XCD swizzle (1024 % 8 == 0): XCD i gets heads 8i..8i+7 (16 blocks/head)
    int orig = blockIdx.x;
    int wg   = (orig & 7) * 128 + (orig >> 3);
    int bh   = wg >> 4, qb = wg & 15;
    int b    = bh >> 4, h = bh & 15;

    int lane = threadIdx.x & 63, wave = threadIdx.x >> 6;
    int g = lane >> 4, c = lane & 15;
    int q0 = qb * 128 + wave * 32;

    int* swv = smem + wave * 4096;

    const float* qbase = Q + (long)(b * S_) * HD_ + h * 64;
    const int*   mbase = M + ((long)bh << 22);
    float*       obase = O + (long)(b * S_) * HD_ + h * 64;
    const short* kpb   = Kp + (long)bh * STEPS_ * 4096;
    const short* vpb   = Vp + (long)bh * STEPS_ * 4096;

    // gll source bases: row-within-group lrow = lane>>4 (0..3).
    // gll i: r = i*4 + lrow; r&7 = (i&1)*4 + lrow. Two lane bases (even/odd i):
    int lrow = lane >> 4;
    int je   = (lane & 15) ^ lrow;         // i even
    int jo   = (lane & 15) ^ (4 + lrow);   // i odd
    const int* src_e = mbase + ((long)(q0 + lrow) << 11) + je * 4;
    const int* src_o = mbase + ((long)(q0 + lrow) << 11) + jo * 4;

    // ---- stage step 0 -> buf 0  (gll i: +i*4 rows = +i*8192 ints; dest +i*256)
#pragma unroll
    for (int i = 0; i < 8; ++i) {
        const int* sp = ((i & 1) ? src_o : src_e) + i * 8192;
        gll16(sp, swv + i * 256);
    }

    // ---- Q fragments (B-operand): lane holds Q[q0+qt*16+c][hf*32+g*8 ..+7] * QSCALE
    short8 qf[2][2];
#pragma unroll
    for (int qt = 0; qt < 2; ++qt) {
        const float* qr = qbase + (long)(q0 + qt * 16 + c) * HD_;
#pragma unroll
        for (int hf = 0; hf < 2; ++hf) {
            f32x4 x0 = *(const f32x4*)(qr + hf * 32 + g * 8);
            f32x4 x1 = *(const f32x4*)(qr + hf * 32 + g * 8 + 4);
            short8 t;
            t[0] = f2bf(x0[0] * QSCALE); t[1] = f2bf(x0[1] * QSCALE);
            t[2] = f2bf(x0[2] * QSCALE); t[3] = f2bf(x0[3] * QSCALE);
            t[4] = f2bf(x1[0] * QSCALE); t[5] = f2bf(x1[1] * QSCALE);
            t[6] = f2bf(x1[2] * QSCALE); t[7] = f2bf(x1[3] * QSCALE);
            qf[qt][hf] = t;
        }
    }

    f32x4 acc[2][4];
#pragma unroll
    for (int qt = 0; qt < 2; ++qt)
#pragma unroll
        for (int dt = 0; dt < 4; ++dt) acc[qt][dt] = (f32x4){0.f, 0.f, 0.f, 0.f};
    float lsum[2] = {0.f, 0.f};

    int c7 = c & 7;

#pragma unroll 1
    for (int s = 0; s < STEPS_; ++s) {
        // 1) K/V fragment loads (L2-resident packed layout) — issued FIRST so
        //    vmcnt(8) retires them without touching the mask prefetch.
        const short* kp = kpb + (long)s * 4096;
        const short* vp = vpb + (long)s * 4096;
        short8 kf[4][2], vf[4][2];
#pragma unroll
        for (int kt = 0; kt < 4; ++kt)
#pragma unroll
            for (int hf = 0; hf < 2; ++hf) {
                kf[kt][hf] = *(const short8*)(kp + ((kt * 2 + hf) * 64 + lane) * 8);
                vf[kt][hf] = *(const short8*)(vp + ((kt * 2 + hf) * 64 + lane) * 8);
            }
        __builtin_amdgcn_sched_barrier(0);

        // 2) async-stage next step's mask into the other buffer (zero VGPR)
        if (s < STEPS_ - 1) {
            int* dst = swv + (((s + 1) & 1) << 11);
            int soff = (s + 1) * 64;
#pragma unroll
            for (int i = 0; i < 8; ++i) {
                const int* sp = ((i & 1) ? src_o : src_e) + i * 8192 + soff;
                gll16(sp, dst + i * 256);
            }
        }

        // 3) counted wait: retire everything except the 8 just-issued gll
        asm volatile("s_waitcnt vmcnt(8)" ::: "memory");
        __builtin_amdgcn_sched_barrier(0);

        // 4) compute on buf[s&1]
        const int* rbuf = swv + ((s & 1) << 11);
#pragma unroll
        for (int qt = 0; qt < 2; ++qt) {
            f32x4 st[4];
#pragma unroll
            for (int kt = 0; kt < 4; ++kt) {
                f32x4 z = (f32x4){0.f, 0.f, 0.f, 0.f};
                z = MFMA(kf[kt][0], qf[qt][0], z);
                z = MFMA(kf[kt][1], qf[qt][1], z);
                st[kt] = z;   // kv = s*64 + kt*16 + g*4 + r, q = q0+qt*16+c
            }

            // mask ints from LDS: row = qt*16+c, slot = (kt*4+g)^(c&7)
            const int* rb = rbuf + (qt * 16 + c) * 64;
            float p[4][4];
            float ssum = 0.f;
#pragma unroll
            for (int kt = 0; kt < 4; ++kt) {
                i32x4 mk = *(const i32x4*)(rb + (((kt * 4 + g) ^ c7) << 2));
#pragma unroll
                for (int r = 0; r < 4; ++r) {
                    float val = (mk[r] != 0) ? st[kt][r] : 0.0f;   // masked -> exp2(0)=1
                    float e = exp2f(val);
                    p[kt][r] = e;
                    ssum += e;
                }
            }
            lsum[qt] += ssum;

            short8 pb0, pb1;
            pb0[0] = f2bf(p[0][0]); pb0[1] = f2bf(p[0][1]); pb0[2] = f2bf(p[0][2]); pb0[3] = f2bf(p[0][3]);
            pb0[4] = f2bf(p[1][0]); pb0[5] = f2bf(p[1][1]); pb0[6] = f2bf(p[1][2]); pb0[7] = f2bf(p[1][3]);
            pb1[0] = f2bf(p[2][0]); pb1[1] = f2bf(p[2][1]); pb1[2] = f2bf(p[2][2]); pb1[3] = f2bf(p[2][3]);
            pb1[4] = f2bf(p[3][0]); pb1[5] = f2bf(p[3][1]); pb1[6] = f2bf(p[3][2]); pb1[7] = f2bf(p[3][3]);

#pragma unroll
            for (int dt = 0; dt < 4; ++dt) {
                acc[qt][dt] = MFMA(vf[dt][0], pb0, acc[qt][dt]);
                acc[qt][dt] = MFMA(vf[dt][1], pb1, acc[qt][dt]);
            }
        }
    }

    // epilogue: reduce row sums across g-groups, normalize, store
#pragma unroll
    for (int qt = 0; qt < 2; ++qt) {
        float t0 = lsum[qt];
        t0 += __shfl_xor(t0, 16);
        t0 += __shfl_xor(t0, 32);
        float inv = 1.0f / t0;
        float* orow = obase + (long)(q0 + qt * 16 + c) * HD_;
#pragma unroll
        for (int dt = 0; dt < 4; ++dt) {
            f32x4 o = acc[qt][dt] * inv;
            __builtin_nontemporal_store(o, (f32x4*)(orow + dt * 16 + g * 4));
        }
    }
}

// ---- fallback (only if ws too small): round-1 style fused kernel ----
__global__ __launch_bounds__(256, 2)
void attn_fwd(const float* __restrict__ Q, const float* __restrict__ K,
              const float* __restrict__ V, const int* __restrict__ M,
              float* __restrict__ O)
{
    const float QSCALE = 0.125f * 1.44269504088896340736f;
    int orig = blockIdx.x;
    int wg   = (orig & 7) * 64 + (orig >> 3);
    int bh   = wg >> 3, qb = wg & 7;
    int b    = bh >> 4, h = bh & 15;
    int lane = threadIdx.x & 63, wave = threadIdx.x >> 6;
    int g = lane >> 4, c = lane & 15;
    int q0 = qb * 256 + wave * 64;

    const float* qbase = Q + (long)(b * S_) * HD_ + h * 64;
    const float* kbase = K + (long)(b * S_) * HD_ + h * 64;
    const float* vbase = V + (long)(b * S_) * HD_ + h * 64;
    const int*   mbase = M + ((long)bh << 22);
    float*       obase = O + (long)(b * S_) * HD_ + h * 64;

    short8 qf[4][2];
#pragma unroll
    for (int qt = 0; qt < 4; ++qt) {
        const float* qr = qbase + (long)(q0 + qt * 16 + c) * HD_;
#pragma unroll
        for (int hf = 0; hf < 2; ++hf) {
            f32x4 x0 = *(const f32x4*)(qr + hf * 32 + g * 8);
            f32x4 x1 = *(const f32x4*)(qr + hf * 32 + g * 8 + 4);
            short8 t;
            t[0] = f2bf(x0[0] * QSCALE); t[1] = f2bf(x0[1] * QSCALE);
            t[2] = f2bf(x0[2] * QSCALE); t[3] = f2bf(x0[3] * QSCALE);
            t[4] = f2bf(x1[0] * QSCALE); t[5] = f2bf(x1[1] * QSCALE);
            t[6] = f2bf(x1[2] * QSCALE); t[7] = f2bf(x1[3] * QSCALE);
            qf[qt][hf] = t;
        }
    }

    f32x4 acc[4][4];
#pragma unroll
    for (int qt = 0; qt < 4; ++qt)
#pragma unroll
        for (int dt = 0; dt < 4; ++dt) acc[qt][dt] = (f32x4){0.f, 0.f, 0.f, 0.f};
    float lsum[4] = {0.f, 0.f, 0.f, 0.f};

#pragma unroll 1
    for (int step = 0; step < 32; ++step) {
        int kv0 = step * 64;
        short8 kf[4][2];
#pragma unroll
        for (int kt = 0; kt < 4; ++kt) {
            const float* kr = kbase + (long)(kv0 + kt * 16 + c) * HD_;
#pragma unroll
            for (int hf = 0; hf < 2; ++hf) {
                f32x4 x0 = *(const f32x4*)(kr + hf * 32 + g * 8);
                f32x4 x1 = *(const f32x4*)(kr + hf * 32 + g * 8 + 4);
                short8 t;
                t[0] = f2bf(x0[0]); t[1] = f2bf(x0[1]); t[2] = f2bf(x0[2]); t[3] = f2bf(x0[3]);
                t[4] = f2bf(x1[0]); t[5] = f2bf(x1[1]); t[6] = f2bf(x1[2]); t[7] = f2bf(x1[3]);
                kf[kt][hf] = t;
            }
        }
        short8 vf[4][2];
#pragma unroll
        for (int hf = 0; hf < 2; ++hf) {
            const float* vr[8];
#pragma unroll
            for (int i = 0; i < 4; ++i) {
                vr[i]     = vbase + (long)(kv0 + hf * 32 + g * 4 + i) * HD_ + c;
                vr[4 + i] = vbase + (long)(kv0 + hf * 32 + 16 + g * 4 + i) * HD_ + c;
            }
#pragma unroll
            for (int dt = 0; dt < 4; ++dt) {
                short8 t;
#pragma unroll
                for (int i = 0; i < 8; ++i) t[i] = f2bf(vr[i][dt * 16]);
                vf[dt][hf] = t;
            }
        }
#pragma unroll
        for (int qt = 0; qt < 4; ++qt) {
            f32x4 st[4];
#pragma unroll
            for (int kt = 0; kt < 4; ++kt) {
                f32x4 z = (f32x4){0.f, 0.f, 0.f, 0.f};
                z = MFMA(kf[kt][0], qf[qt][0], z);
                z = MFMA(kf[kt][1], qf[qt][1], z);
                st[kt] = z;
            }
            const int* mrp = mbase + ((long)(q0 + qt * 16 + c) << 11) + kv0 + g * 4;
            float p[4][4];
            float s = 0.f;
#pragma unroll
            for (int kt = 0; kt < 4; ++kt) {
                i32x4 mkv = *(const i32x4*)(mrp + kt * 16);
#pragma unroll
                for (int r = 0; r < 4; ++r) {
                    float val = (mkv[r] != 0) ? st[kt][r] : 0.0f;
                    float e = exp2f(val);
                    p[kt][r] = e;
                    s += e;
                }
            }
            lsum[qt] += s;
            short8 pb0, pb1;
            pb0[0] = f2bf(p[0][0]); pb0[1] = f2bf(p[0][1]); pb0[2] = f2bf(p[0][2]); pb0[3] = f2bf(p[0][3]);
            pb0[4] = f2bf(p[1][0]); pb0[5] = f2bf(p[1][1]); pb0[6] = f2bf(p[1][2]); pb0[7] = f2bf(p[1][3]);
            pb1[0] = f2bf(p[2][0]); pb1[1] = f2bf(p[2][1]); pb1[2] = f2bf(p[2][2]); pb1[3] = f2bf(p[2][3]);
            pb1[4] = f2bf(p[3][0]); pb1[5] = f2bf(p[3][1]); pb1[6] = f2bf(p[3][2]); pb1[7] = f2bf(p[3][3]);
#pragma unroll
            for (int dt = 0; dt < 4; ++dt) {
                acc[qt][dt] = MFMA(vf[dt][0], pb0, acc[qt][dt]);
                acc[qt][dt] = MFMA(vf[dt][1], pb1, acc[qt][dt]);
            }
        }
    }
#pragma unroll
    for (int qt = 0; qt < 4; ++qt) {
        float t0 = lsum[qt];
        t0 += __shfl_xor(t0, 16);
        t0 += __shfl_xor(t0, 32);
        float inv = 1.0f / t0;
        float* orow = obase + (long)(q0 + qt * 16 + c) * HD_;
#pragma unroll
        for (int dt = 0; dt < 4; ++dt) {
            f32x4 o = acc[qt][dt] * inv;
            *(f32x4*)(orow + dt * 16 + g * 4) = o;
        }
    }
}

extern "C" void kernel_launch(void* const* d_in, const int* in_sizes, int n_in,
                              void* d_out, int out_size, void* d_ws, size_t ws_size,
                              hipStream_t stream) {
    const float* q = (const float*)d_in[0];
    const float* k = (const float*)d_in[1];
    const float* v = (const float*)d_in[2];
    const int*   m = (const int*)d_in[3];
    float* out = (float*)d_out;

    size_t need = (size_t)2 * KP_ELEMS * sizeof(short);   // 32 MiB
    if (ws_size >= need) {
        short* Kp = (short*)d_ws;
        short* Vp = Kp + KP_ELEMS;
        prepack_kv<<<dim3(4096), dim3(256), 0, stream>>>(k, v, Kp, Vp);
        attn_gll<<<dim3(1024), dim3(256), 0, stream>>>(q, Kp, Vp, m, out);
    } else {
        attn_fwd<<<dim3(512), dim3(256), 0, stream>>>(q, k, v, m, out);
    }
}

// Round 14
// 242.645 us; speedup vs baseline: 1.1497x; 1.1497x over previous
//
#include <hip/hip_runtime.h>

// B=4,S=2048,H=16,D=64. scores/8, mask->1e-20(~0), softmax, PV.
// FINAL (= round-8 winner, 242us): HBM-bound pipelined kernel using
// global_load_lds (zero-VGPR mask prefetch). Step=32 kv. Per step: load K/V
// frags (L2-resident prepacked), async-stage next step's raw mask (8KB/wave)
// into LDS double-buffer via 8x gll16 with pre-swizzled per-lane source
// (XOR granule swizzle -> conflict-free i32x4 reads), counted s_waitcnt
// vmcnt(8), compute. No barriers, no compression, no register prefetch.
// Compute hides under the 1.07GB mask stream (~5.3 TB/s, ~82% of achievable;
// R9-R13 measured cache-policy/occupancy/L2-traffic/granularity levers all
// neutral or negative -> this is the structural optimum of the design space).
// Masked positions -> exp2(0)=1, matching ref's 1e-20 pre-softmax semantics.

typedef __attribute__((ext_vector_type(8))) short short8;
typedef __attribute__((ext_vector_type(4))) float f32x4;
typedef __attribute__((ext_vector_type(4))) int   i32x4;
typedef unsigned int u32;

#define MFMA(a, b, c) __builtin_amdgcn_mfma_f32_16x16x32_bf16((a), (b), (c), 0, 0, 0)

static __device__ __forceinline__ short f2bf(float f) {
    __bf16 h = (__bf16)f;
    return __builtin_bit_cast(short, h);
}

static __device__ __forceinline__ void gll16(const int* src, int* dst) {
    __builtin_amdgcn_global_load_lds(
        (const __attribute__((address_space(1))) void*)src,
        (__attribute__((address_space(3))) void*)dst, 16, 0, 0);
}

constexpr int S_ = 2048, HD_ = 1024;
constexpr long KP_ELEMS = 64L * 32 * 4 * 2 * 64 * 8;   // 8,388,608 bf16 per tensor

// ---- prepack: thread t packs K-fragment t and V-fragment t.
__global__ __launch_bounds__(256) void prepack_kv(const float* __restrict__ K,
                                                  const float* __restrict__ V,
                                                  short* __restrict__ Kp,
                                                  short* __restrict__ Vp) {
    int t = blockIdx.x * 256 + threadIdx.x;
    int lane = t & 63, hf = (t >> 6) & 1, kt = (t >> 7) & 3, step = (t >> 9) & 31, bh = t >> 14;
    int g = lane >> 4, c = lane & 15, b = bh >> 4, h = bh & 15;

    {   // K: lane holds K[b, step*64+kt*16+c, h, hf*32+g*8 .. +7]
        int row = step * 64 + kt * 16 + c;
        const float* src = K + (long)(b * S_ + row) * HD_ + h * 64 + hf * 32 + g * 8;
        f32x4 x0 = *(const f32x4*)src, x1 = *(const f32x4*)(src + 4);
        short8 o;
        o[0] = f2bf(x0[0]); o[1] = f2bf(x0[1]); o[2] = f2bf(x0[2]); o[3] = f2bf(x0[3]);
        o[4] = f2bf(x1[0]); o[5] = f2bf(x1[1]); o[6] = f2bf(x1[2]); o[7] = f2bf(x1[3]);
        *(short8*)(Kp + (long)t * 8) = o;
    }
    {   // V (kt plays dt): kappa-ordered V^T fragment
        int col = kt * 16 + c, row0 = step * 64 + hf * 32;
        const float* vb = V + (long)(b * S_) * HD_ + h * 64 + col;
        short8 o;
#pragma unroll
        for (int i = 0; i < 8; ++i) {
            int row = row0 + ((i < 4) ? g * 4 + i : 16 + g * 4 + (i - 4));
            o[i] = f2bf(vb[(long)row * HD_]);
        }
        *(short8*)(Vp + (long)t * 8) = o;
    }
}

// ---- main kernel: 512 blocks x 256 thr; wave owns 64 q-rows; 64 steps of 32 kv.
// Per-wave LDS: 2 bufs x 2048 ints (8KB). Buf layout in 16B granules:
//   granule (row, gslot) holds mask ints of (q0+row, step*32 + gi*4 .. +3),
//   gi = gslot ^ (row & 7)   [XOR swizzle, staged via pre-swizzled global src].
__global__ __launch_bounds__(256, 2)
void attn_gll(const float* __restrict__ Q, const short* __restrict__ Kp,
              const short* __restrict__ Vp, const int* __restrict__ M,
              float* __restrict__ O)
{
    const float QSCALE = 0.125f * 1.44269504088896340736f;  // 1/sqrt(64) * log2(e)

    __shared__ int smem[16384];   // 64 KiB: 4 waves x 2 bufs x 2048 ints

    // XCD swizzle: XCD i gets bh 8i..8i+7; all 8 q-blocks of a head co-resident
    int orig = blockIdx.x;
    int wg   = (orig & 7) * 64 + (orig >> 3);
    int bh   = wg >> 3, qb = wg & 7;
    int b    = bh >> 4, h = bh & 15;

    int lane = threadIdx.x & 63, wave = threadIdx.x >> 6;
    int g = lane >> 4, c = lane & 15;
    int q0 = qb * 256 + wave * 64;

    int* swv = smem + wave * 4096;

    const float* qbase = Q + (long)(b * S_) * HD_ + h * 64;
    const int*   mbase = M + ((long)bh << 22);
    float*       obase = O + (long)(b * S_) * HD_ + h * 64;
    const short* kpb   = Kp + (long)bh * 32 * 4096;
    const short* vpb   = Vp + (long)bh * 32 * 4096;

    // per-lane gll source base: instr i, step s reads granule for
    // row = i*8 + (lane>>3), gi = (lane&7) ^ ((lane>>3)&7)
    int lrow = lane >> 3;
    int lgi  = (lane & 7) ^ lrow;
    const int* lane_src = mbase + ((long)(q0 + lrow) << 11) + lgi * 4;

    // ---- stage step 0 -> buf 0
#pragma unroll
    for (int i = 0; i < 8; ++i)
        gll16(lane_src + i * 16384, swv + i * 256);

    // ---- Q fragments (B-operand): lane holds Q[q0+qt*16+c][hf*32+g*8 ..+7] * QSCALE
    short8 qf[4][2];
#pragma unroll
    for (int qt = 0; qt < 4; ++qt) {
        const float* qr = qbase + (long)(q0 + qt * 16 + c) * HD_;
#pragma unroll
        for (int hf = 0; hf < 2; ++hf) {
            f32x4 x0 = *(const f32x4*)(qr + hf * 32 + g * 8);
            f32x4 x1 = *(const f32x4*)(qr + hf * 32 + g * 8 + 4);
            short8 t;
            t[0] = f2bf(x0[0] * QSCALE); t[1] = f2bf(x0[1] * QSCALE);
            t[2] = f2bf(x0[2] * QSCALE); t[3] = f2bf(x0[3] * QSCALE);
            t[4] = f2bf(x1[0] * QSCALE); t[5] = f2bf(x1[1] * QSCALE);
            t[6] = f2bf(x1[2] * QSCALE); t[7] = f2bf(x1[3] * QSCALE);
            qf[qt][hf] = t;
        }
    }

    f32x4 acc[4][4];
#pragma unroll
    for (int qt = 0; qt < 4; ++qt)
#pragma unroll
        for (int dt = 0; dt < 4; ++dt) acc[qt][dt] = (f32x4){0.f, 0.f, 0.f, 0.f};
    float lsum[4] = {0.f, 0.f, 0.f, 0.f};

    int c7 = c & 7;
    int gs0 = (g ^ c7) << 2;            // int offset of kt=0 granule within row
    int gs1 = ((4 + g) ^ c7) << 2;      // kt=1

#pragma unroll 1
    for (int s = 0; s < 64; ++s) {
        int s64 = s >> 1, half = s & 1;

        // 1) K/V fragment loads (L2-resident packed layout) — issued FIRST so
        //    vmcnt(8) retires them without touching the mask prefetch.
        const short* kp2 = kpb + (long)s64 * 4096 + half * 2048;
        const short* vp2 = vpb + (long)s64 * 4096 + half * 512;
        short8 kf[2][2], vf[4];
#pragma unroll
        for (int kt = 0; kt < 2; ++kt)
#pragma unroll
            for (int hf = 0; hf < 2; ++hf)
                kf[kt][hf] = *(const short8*)(kp2 + kt * 1024 + hf * 512 + lane * 8);
#pragma unroll
        for (int dt = 0; dt < 4; ++dt)
            vf[dt] = *(const short8*)(vp2 + dt * 1024 + lane * 8);
        __builtin_amdgcn_sched_barrier(0);

        // 2) async-stage next step's mask into the other buffer (zero VGPR)
        if (s < 63) {
            int* dst = swv + (((s + 1) & 1) << 11);
            const int* sp = lane_src + (long)(s + 1) * 32;
#pragma unroll
            for (int i = 0; i < 8; ++i)
                gll16(sp + i * 16384, dst + i * 256);
        }

        // 3) counted wait: retire everything except the 8 just-issued gll
        asm volatile("s_waitcnt vmcnt(8)" ::: "memory");
        __builtin_amdgcn_sched_barrier(0);

        // 4) compute on buf[s&1]
        const int* rbuf = swv + ((s & 1) << 11);
#pragma unroll
        for (int qt = 0; qt < 4; ++qt) {
            f32x4 z = (f32x4){0.f, 0.f, 0.f, 0.f};
            f32x4 st0 = MFMA(kf[0][1], qf[qt][1], MFMA(kf[0][0], qf[qt][0], z));
            f32x4 st1 = MFMA(kf[1][1], qf[qt][1], MFMA(kf[1][0], qf[qt][0], z));
            // kv = s*32 + kt*16 + g*4 + r, q = q0 + qt*16 + c (log2e-scaled)

            int row = qt * 16 + c;
            i32x4 mk0 = *(const i32x4*)(rbuf + row * 32 + gs0);
            i32x4 mk1 = *(const i32x4*)(rbuf + row * 32 + gs1);

            float p0[4], p1[4], ssum = 0.f;
#pragma unroll
            for (int r = 0; r < 4; ++r) {
                float v0 = (mk0[r] != 0) ? st0[r] : 0.0f;   // masked -> exp2(0)=1
                float v1 = (mk1[r] != 0) ? st1[r] : 0.0f;
                float e0 = exp2f(v0), e1 = exp2f(v1);
                p0[r] = e0; p1[r] = e1;
                ssum += e0 + e1;
            }
            lsum[qt] += ssum;

            short8 pb;
            pb[0] = f2bf(p0[0]); pb[1] = f2bf(p0[1]); pb[2] = f2bf(p0[2]); pb[3] = f2bf(p0[3]);
            pb[4] = f2bf(p1[0]); pb[5] = f2bf(p1[1]); pb[6] = f2bf(p1[2]); pb[7] = f2bf(p1[3]);

#pragma unroll
            for (int dt = 0; dt < 4; ++dt)
                acc[qt][dt] = MFMA(vf[dt], pb, acc[qt][dt]);
        }
    }

    // epilogue: reduce row sums across g-groups, normalize, store
#pragma unroll
    for (int qt = 0; qt < 4; ++qt) {
        float t0 = lsum[qt];
        t0 += __shfl_xor(t0, 16);
        t0 += __shfl_xor(t0, 32);
        float inv = 1.0f / t0;
        float* orow = obase + (long)(q0 + qt * 16 + c) * HD_;
#pragma unroll
        for (int dt = 0; dt < 4; ++dt) {
            f32x4 o = acc[qt][dt] * inv;
            __builtin_nontemporal_store(o, (f32x4*)(orow + dt * 16 + g * 4));
        }
    }
}

// ---- fallback (only if ws too small): round-1 style fused kernel ----
__global__ __launch_bounds__(256, 2)
void attn_fwd(const float* __restrict__ Q, const float* __restrict__ K,
              const float* __restrict__ V, const int* __restrict__ M,
              float* __restrict__ O)
{
    const float QSCALE = 0.125f * 1.44269504088896340736f;
    int orig = blockIdx.x;
    int wg   = (orig & 7) * 64 + (orig >> 3);
    int bh   = wg >> 3, qb = wg & 7;
    int b    = bh >> 4, h = bh & 15;
    int lane = threadIdx.x & 63, wave = threadIdx.x >> 6;
    int g = lane >> 4, c = lane & 15;
    int q0 = qb * 256 + wave * 64;

    const float* qbase = Q + (long)(b * S_) * HD_ + h * 64;
    const float* kbase = K + (long)(b * S_) * HD_ + h * 64;
    const float* vbase = V + (long)(b * S_) * HD_ + h * 64;
    const int*   mbase = M + ((long)bh << 22);
    float*       obase = O + (long)(b * S_) * HD_ + h * 64;

    short8 qf[4][2];
#pragma unroll
    for (int qt = 0; qt < 4; ++qt) {
        const float* qr = qbase + (long)(q0 + qt * 16 + c) * HD_;
#pragma unroll
        for (int hf = 0; hf < 2; ++hf) {
            f32x4 x0 = *(const f32x4*)(qr + hf * 32 + g * 8);
            f32x4 x1 = *(const f32x4*)(qr + hf * 32 + g * 8 + 4);
            short8 t;
            t[0] = f2bf(x0[0] * QSCALE); t[1] = f2bf(x0[1] * QSCALE);
            t[2] = f2bf(x0[2] * QSCALE); t[3] = f2bf(x0[3] * QSCALE);
            t[4] = f2bf(x1[0] * QSCALE); t[5] = f2bf(x1[1] * QSCALE);
            t[6] = f2bf(x1[2] * QSCALE); t[7] = f2bf(x1[3] * QSCALE);
            qf[qt][hf] = t;
        }
    }

    f32x4 acc[4][4];
#pragma unroll
    for (int qt = 0; qt < 4; ++qt)
#pragma unroll
        for (int dt = 0; dt < 4; ++dt) acc[qt][dt] = (f32x4){0.f, 0.f, 0.f, 0.f};
    float lsum[4] = {0.f, 0.f, 0.f, 0.f};

#pragma unroll 1
    for (int step = 0; step < 32; ++step) {
        int kv0 = step * 64;
        short8 kf[4][2];
#pragma unroll
        for (int kt = 0; kt < 4; ++kt) {
            const float* kr = kbase + (long)(kv0 + kt * 16 + c) * HD_;
#pragma unroll
            for (int hf = 0; hf < 2; ++hf) {
                f32x4 x0 = *(const f32x4*)(kr + hf * 32 + g * 8);
                f32x4 x1 = *(const f32x4*)(kr + hf * 32 + g * 8 + 4);
                short8 t;
                t[0] = f2bf(x0[0]); t[1] = f2bf(x0[1]); t[2] = f2bf(x0[2]); t[3] = f2bf(x0[3]);
                t[4] = f2bf(x1[0]); t[5] = f2bf(x1[1]); t[6] = f2bf(x1[2]); t[7] = f2bf(x1[3]);
                kf[kt][hf] = t;
            }
        }
        short8 vf[4][2];
#pragma unroll
        for (int hf = 0; hf < 2; ++hf) {
            const float* vr[8];
#pragma unroll
            for (int i = 0; i < 4; ++i) {
                vr[i]     = vbase + (long)(kv0 + hf * 32 + g * 4 + i) * HD_ + c;
                vr[4 + i] = vbase + (long)(kv0 + hf * 32 + 16 + g * 4 + i) * HD_ + c;
            }
#pragma unroll
            for (int dt = 0; dt < 4; ++dt) {
                short8 t;
#pragma unroll
                for (int i = 0; i < 8; ++i) t[i] = f2bf(vr[i][dt * 16]);
                vf[dt][hf] = t;
            }
        }
#pragma unroll
        for (int qt = 0; qt < 4; ++qt) {
            f32x4 st[4];
#pragma unroll
            for (int kt = 0; kt < 4; ++kt) {
                f32x4 z = (f32x4){0.f, 0.f, 0.f, 0.f};
                z = MFMA(kf[kt][0], qf[qt][0], z);
                z = MFMA(kf[kt][1], qf[qt][1], z);
                st[kt] = z;
            }
            const int* mrp = mbase + ((long)(q0 + qt * 16 + c) << 11) + kv0 + g * 4;
            float p[4][4];
            float s = 0.f;
#pragma unroll
            for (int kt = 0; kt < 4; ++kt) {
                i32x4 mkv = *(const i32x4*)(mrp + kt * 16);
#pragma unroll
                for (int r = 0; r < 4; ++r) {
                    float val = (mkv[r] != 0) ? st[kt][r] : 0.0f;
                    float e = exp2f(val);
                    p[kt][r] = e;
                    s += e;
                }
            }
            lsum[qt] += s;
            short8 pb0, pb1;
            pb0[0] = f2bf(p[0][0]); pb0[1] = f2bf(p[0][1]); pb0[2] = f2bf(p[0][2]); pb0[3] = f2bf(p[0][3]);
            pb0[4] = f2bf(p[1][0]); pb0[5] = f2bf(p[1][1]); pb0[6] = f2bf(p[1][2]); pb0[7] = f2bf(p[1][3]);
            pb1[0] = f2bf(p[2][0]); pb1[1] = f2bf(p[2][1]); pb1[2] = f2bf(p[2][2]); pb1[3] = f2bf(p[2][3]);
            pb1[4] = f2bf(p[3][0]); pb1[5] = f2bf(p[3][1]); pb1[6] = f2bf(p[3][2]); pb1[7] = f2bf(p[3][3]);
#pragma unroll
            for (int dt = 0; dt < 4; ++dt) {
                acc[qt][dt] = MFMA(vf[dt][0], pb0, acc[qt][dt]);
                acc[qt][dt] = MFMA(vf[dt][1], pb1, acc[qt][dt]);
            }
        }
    }
#pragma unroll
    for (int qt = 0; qt < 4; ++qt) {
        float t0 = lsum[qt];
        t0 += __shfl_xor(t0, 16);
        t0 += __shfl_xor(t0, 32);
        float inv = 1.0f / t0;
        float* orow = obase + (long)(q0 + qt * 16 + c) * HD_;
#pragma unroll
        for (int dt = 0; dt < 4; ++dt) {
            f32x4 o = acc[qt][dt] * inv;
            *(f32x4*)(orow + dt * 16 + g * 4) = o;
        }
    }
}

extern "C" void kernel_launch(void* const* d_in, const int* in_sizes, int n_in,
                              void* d_out, int out_size, void* d_ws, size_t ws_size,
                              hipStream_t stream) {
    const float* q = (const float*)d_in[0];
    const float* k = (const float*)d_in[1];
    const float* v = (const float*)d_in[2];
    const int*   m = (const int*)d_in[3];
    float* out = (float*)d_out;

    size_t need = (size_t)2 * KP_ELEMS * sizeof(short);   // 32 MiB
    if (ws_size >= need) {
        short* Kp = (short*)d_ws;
        short* Vp = Kp + KP_ELEMS;
        prepack_kv<<<dim3(4096), dim3(256), 0, stream>>>(k, v, Kp, Vp);
        attn_gll<<<dim3(512), dim3(256), 0, stream>>>(q, Kp, Vp, m, out);
    } else {
        attn_fwd<<<dim3(512), dim3(256), 0, stream>>>(q, k, v, m, out);
    }
}